// Round 3
// baseline (370.894 us; speedup 1.0000x reference)
//
#include <hip/hip_runtime.h>
#include <math.h>

#define EPS 1e-5f
// dims: n=8, C=512, t=8, h=32, w=32, K=8, S=4 (hb=wb=8), TS=2 (tb=4), TK=8

typedef __bf16 bf16x8 __attribute__((ext_vector_type(8)));
typedef float f32x4 __attribute__((ext_vector_type(4)));

__device__ static inline unsigned short f2bf(float f) {
    unsigned u = __float_as_uint(f);
    unsigned r = (u + 0x7fffu + ((u >> 16) & 1u)) >> 16;  // RNE
    return (unsigned short)r;
}

__device__ static inline void load_lds16(const void* g, void* l) {
    __builtin_amdgcn_global_load_lds(
        (const __attribute__((address_space(1))) unsigned int*)g,
        (__attribute__((address_space(3))) unsigned int*)l, 16, 0, 0);
}

// ---------------------------------------------------------------------------
// K1: conv1(512->8)+BN1+ReLU on the fly; pools rp/cp/tp. Folds w2 fp32->bf16.
// (unchanged)
// ---------------------------------------------------------------------------
__global__ __launch_bounds__(512) void k_conv1_pool(
    const float* __restrict__ x,  const float* __restrict__ w1,
    const float* __restrict__ b1, const float* __restrict__ g1,
    const float* __restrict__ bb1,const float* __restrict__ m1,
    const float* __restrict__ v1,
    const float* __restrict__ w2, unsigned short* __restrict__ w2bf,
    float* __restrict__ rp, float* __restrict__ cp, float* __restrict__ tps)
{
    const int a   = blockIdx.x;   // 0..3 (h-block)
    const int t   = blockIdx.y;   // 0..7
    const int nn  = blockIdx.z;   // 0..7
    const int tid = threadIdx.x;  // 0..511
    const int wv  = tid >> 6;     // wave = output k
    const int lane= tid & 63;

    __shared__ float xs[2][8192];  // 2 x 32 KB: [buf][c(32)][pos(256)]

    // folded w2 cast (1 MB read total across grid)
    {
        int gid = (((nn * 8 + t) * 4 + a) * 512) + tid;
        if (gid < 65536) {
            float4 v = *(const float4*)&w2[gid * 4];
            ushort4 o;
            o.x = f2bf(v.x); o.y = f2bf(v.y); o.z = f2bf(v.z); o.w = f2bf(v.w);
            *(ushort4*)&w2bf[gid * 4] = o;
        }
    }

    const int k = __builtin_amdgcn_readfirstlane(wv);
    const float* xg = x + (size_t)nn * 512 * 8192 + t * 1024 + a * 256 + lane * 4;

#pragma unroll
    for (int i = 0; i < 4; i++) {
        int r = i * 8 + wv;
        load_lds16(xg + (size_t)r * 8192, &xs[0][r * 256]);
    }
    __syncthreads();

    f32x4 acc = (f32x4){0.f, 0.f, 0.f, 0.f};
    const float* wk = w1 + k * 512;   // wave-uniform -> s_load

    for (int ch = 0; ch < 16; ch++) {
        const int cur = ch & 1;
        if (ch < 15) {
#pragma unroll
            for (int i = 0; i < 4; i++) {
                int r = i * 8 + wv;
                load_lds16(xg + (size_t)((ch + 1) * 32 + r) * 8192,
                           &xs[cur ^ 1][r * 256]);
            }
        }
#pragma unroll
        for (int c = 0; c < 32; c++) {
            f32x4 xv = *(const f32x4*)&xs[cur][c * 256 + lane * 4];
            float wt = wk[ch * 32 + c];
            acc[0] += wt * xv[0];
            acc[1] += wt * xv[1];
            acc[2] += wt * xv[2];
            acc[3] += wt * xv[3];
        }
        __syncthreads();
    }

    {
        const float sc = g1[k] * rsqrtf(v1[k] + EPS);
        const float ba = (b1[k] - m1[k]) * sc + bb1[k];
        float o0 = fmaxf(acc[0] * sc + ba, 0.f);
        float o1 = fmaxf(acc[1] * sc + ba, 0.f);
        float o2 = fmaxf(acc[2] * sc + ba, 0.f);
        float o3 = fmaxf(acc[3] * sc + ba, 0.f);

        float m4 = fmaxf(fmaxf(o0, o1), fmaxf(o2, o3));
        float s4 = o0 + o1 + o2 + o3;

        float mr = m4;
#pragma unroll
        for (int m = 32; m >= 1; m >>= 1) mr = fmaxf(mr, __shfl_xor(mr, m, 64));
        if (lane == 0) rp[((nn * 8 + k) * 8 + t) * 4 + a] = mr;

        float mc = m4;
        mc = fmaxf(mc, __shfl_xor(mc, 1, 64));
        mc = fmaxf(mc, __shfl_xor(mc, 8, 64));
        mc = fmaxf(mc, __shfl_xor(mc, 16, 64));
        mc = fmaxf(mc, __shfl_xor(mc, 32, 64));
        if ((lane & 0x39) == 0)
            atomicMax((int*)&cp[((nn * 8 + k) * 8 + t) * 4 + (lane >> 1)],
                      __float_as_int(mc));

        float ss = s4;
#pragma unroll
        for (int m = 32; m >= 1; m >>= 1) ss += __shfl_xor(ss, m, 64);
        if (lane == 0) atomicAdd(&tps[(nn * 8 + k) * 2 + (t >> 2)], ss);
    }
}

// ---------------------------------------------------------------------------
// K2: conv_p/conv_q/conv_t + softmaxes -> P, Q, TM. grid (n=8), 256 threads.
// (unchanged)
// ---------------------------------------------------------------------------
__global__ __launch_bounds__(256) void k_pqtm(
    const float* __restrict__ rp, const float* __restrict__ cp,
    const float* __restrict__ tps,
    const float* __restrict__ pw, const float* __restrict__ pb,
    const float* __restrict__ qw, const float* __restrict__ qb,
    const float* __restrict__ tw, const float* __restrict__ tbv,
    float* __restrict__ P, float* __restrict__ Q, float* __restrict__ TM)
{
    const int nn  = blockIdx.x;
    const int tid = threadIdx.x;
    __shared__ float rps[256], cps[256], tpss[16];
    rps[tid] = rp[nn * 256 + tid];
    cps[tid] = cp[nn * 256 + tid];
    if (tid < 16) tpss[tid] = tps[nn * 16 + tid] * (1.0f / 4096.0f);
    __syncthreads();

    {   // p: tid = k*32 + a*8 + t; softmax over b
        int k = tid >> 5, a = (tid >> 3) & 3, t = tid & 7;
        float v[4];
#pragma unroll
        for (int b = 0; b < 4; b++) {
            int o = k * 16 + a * 4 + b;
            float s = pb[o];
#pragma unroll
            for (int c = 0; c < 8; c++)
#pragma unroll
                for (int i = 0; i < 4; i++)
                    s += pw[o * 32 + c * 4 + i] * rps[c * 32 + t * 4 + i];
            v[b] = s;
        }
        float mx = fmaxf(fmaxf(v[0], v[1]), fmaxf(v[2], v[3]));
        float e[4]; float sum = 0.f;
#pragma unroll
        for (int b = 0; b < 4; b++) { e[b] = expf(v[b] - mx); sum += e[b]; }
        float inv = 1.f / sum;
        int base = ((nn * 8 + k) * 8 + t) * 16 + a * 4;
#pragma unroll
        for (int b = 0; b < 4; b++) P[base + b] = e[b] * inv;
    }
    {   // q: tid = k*32 + b*8 + t; softmax over a
        int k = tid >> 5, b = (tid >> 3) & 3, t = tid & 7;
        float v[4];
#pragma unroll
        for (int a = 0; a < 4; a++) {
            int o = k * 16 + a * 4 + b;
            float s = qb[o];
#pragma unroll
            for (int c = 0; c < 8; c++)
#pragma unroll
                for (int i = 0; i < 4; i++)
                    s += qw[o * 32 + c * 4 + i] * cps[c * 32 + t * 4 + i];
            v[a] = s;
        }
        float mx = fmaxf(fmaxf(v[0], v[1]), fmaxf(v[2], v[3]));
        float e[4]; float sum = 0.f;
#pragma unroll
        for (int a = 0; a < 4; a++) { e[a] = expf(v[a] - mx); sum += e[a]; }
        float inv = 1.f / sum;
        int base = ((nn * 8 + k) * 8 + t) * 16 + b;
#pragma unroll
        for (int a = 0; a < 4; a++) Q[base + a * 4] = e[a] * inv;
    }
    if (tid < 16) {  // tm
        int kk = tid >> 1, a2 = tid & 1;
        float v[2];
#pragma unroll
        for (int b2 = 0; b2 < 2; b2++) {
            int o = kk * 4 + a2 * 2 + b2;
            float s = tbv[o];
#pragma unroll
            for (int c = 0; c < 8; c++)
#pragma unroll
                for (int i = 0; i < 2; i++)
                    s += tw[o * 16 + c * 2 + i] * tpss[c * 2 + i];
            v[b2] = s;
        }
        float mx = fmaxf(v[0], v[1]);
        float e0 = expf(v[0] - mx), e1 = expf(v[1] - mx);
        float inv = 1.f / (e0 + e1);
        TM[nn * 32 + kk * 4 + a2 * 2 + 0] = e0 * inv;
        TM[nn * 32 + kk * 4 + a2 * 2 + 1] = e1 * inv;
    }
}

// ---------------------------------------------------------------------------
// K3a: block-linear mixing -> y3T[n][p][c] (bf16, k-major). (unchanged)
// grid (u2*8+u = 32, cg32 = 16, n = 8) = 4096 blocks, 256 threads.
// ---------------------------------------------------------------------------
__global__ __launch_bounds__(256) void k_mix(
    const float* __restrict__ x, const float* __restrict__ P,
    const float* __restrict__ Q, const float* __restrict__ TM,
    unsigned short* __restrict__ y3T)
{
    const int u2  = blockIdx.x >> 3;   // 0..3 (t-pair)
    const int u   = blockIdx.x & 7;    // 0..7 (row-within-h-block)
    const int cg  = blockIdx.y;        // 0..15 (32-channel group)
    const int nn  = blockIdx.z;        // 0..7
    const int tid = threadIdx.x;       // 0..255
    const int kc  = cg >> 1;           // 64-chan group index for P/Q/TM

    __shared__ float xs[8192];             // 32 KB: 256 rows x 32 w, swizzled
    __shared__ unsigned short ys[8192];    // 16 KB: [tt][a][w][c32]

    const size_t xbase = (size_t)nn * 512 * 8192 + (size_t)cg * 32 * 8192;
#pragma unroll
    for (int rr = 0; rr < 8; rr++) {
        int id  = rr * 256 + tid;
        int row = id >> 3;                 // (tt*4+b)*32 + c
        int jw  = (id & 7) ^ (row & 7);    // swizzled w-chunk
        int tt = row >> 7, b = (row >> 5) & 3, c = row & 31;
        load_lds16(x + xbase + (size_t)c * 8192
                     + (u2 + 4 * tt) * 1024 + (b * 8 + u) * 32 + jw * 4,
                   &xs[(rr * 256 + (tid & 192)) * 4]);
    }

    const int a = tid >> 6, vh = (tid >> 5) & 1, c = tid & 31;
    float Pt[2][4], Qt[2][4][4];
#pragma unroll
    for (int tt = 0; tt < 2; tt++) {
        const float* Pb = &P[((nn * 8 + kc) * 8 + (u2 + 4 * tt)) * 16];
        const float* Qb = &Q[((nn * 8 + kc) * 8 + (u2 + 4 * tt)) * 16];
#pragma unroll
        for (int b = 0; b < 4; b++) Pt[tt][b] = Pb[a * 4 + b];
#pragma unroll
        for (int aw = 0; aw < 4; aw++)
#pragma unroll
            for (int bw = 0; bw < 4; bw++) Qt[tt][aw][bw] = Qb[aw * 4 + bw];
    }
    const float* TMb = &TM[nn * 32 + kc * 4];
    const float tm00 = TMb[0], tm01 = TMb[1], tm10 = TMb[2], tm11 = TMb[3];
    __syncthreads();

    float y1[2][4][4];
#pragma unroll
    for (int tt = 0; tt < 2; tt++)
#pragma unroll
        for (int aw = 0; aw < 4; aw++)
#pragma unroll
            for (int vi = 0; vi < 4; vi++) y1[tt][aw][vi] = 0.f;
#pragma unroll
    for (int tt = 0; tt < 2; tt++) {
#pragma unroll
        for (int b = 0; b < 4; b++) {
            float pv = Pt[tt][b];
            int row = (tt * 4 + b) * 32 + c;
#pragma unroll
            for (int aw = 0; aw < 4; aw++) {
                int slot = (aw * 2 + vh) ^ (c & 7);
                float4 xv = *(const float4*)&xs[(row * 8 + slot) * 4];
                y1[tt][aw][0] += pv * xv.x;
                y1[tt][aw][1] += pv * xv.y;
                y1[tt][aw][2] += pv * xv.z;
                y1[tt][aw][3] += pv * xv.w;
            }
        }
    }
#pragma unroll
    for (int bw = 0; bw < 4; bw++) {
#pragma unroll
        for (int vi = 0; vi < 4; vi++) {
            float s0 = 0.f, s1 = 0.f;
#pragma unroll
            for (int aw = 0; aw < 4; aw++) {
                s0 += Qt[0][aw][bw] * y1[0][aw][vi];
                s1 += Qt[1][aw][bw] * y1[1][aw][vi];
            }
            int wout = bw * 8 + vh * 4 + vi;
            ys[((0 + a) * 32 + wout) * 32 + c] = f2bf(tm00 * s0 + tm01 * s1);
            ys[((4 + a) * 32 + wout) * 32 + c] = f2bf(tm10 * s0 + tm11 * s1);
        }
    }
    __syncthreads();

#pragma unroll
    for (int it = 0; it < 4; it++) {
        int id  = it * 256 + tid;
        int row = id >> 2, jc = id & 3;    // row = (tt*4+a)*32 + w
        int tt = row >> 7, aa = (row >> 5) & 3, w = row & 31;
        int p = (u2 + 4 * tt) * 1024 + (aa * 8 + u) * 32 + w;
        uint4 val = *(const uint4*)&ys[row * 32 + jc * 8];
        *(uint4*)&y3T[((size_t)nn * 8192 + p) * 512 + cg * 32 + jc * 8] = val;
    }
}

// ---------------------------------------------------------------------------
// K3b: conv2 + BN2 + ReLU, persistent-A bf16 MFMA GEMM.
// R3 FIXES (from R2 counters: 4.19M bank conflicts = 8/B-frag-read; 2600
// cyc/iter exposed fetch):
//  (1) Bs chunk-major [q(4)][prow(256)] -> B-frag read slot = ln15&7,
//      conflict-free (same class as As read, which measured ~0).
//  (2) Bs double-buffered (2x16 KB), stage(it+1) issued BEFORE compute(it),
//      ONE __syncthreads per iter -> 16 KB fetch in flight under compute.
// LDS = 128 + 32 = 160 KB (full pool; AITER/HK run 160 KB WGs on gfx950).
// ---------------------------------------------------------------------------
__global__ __launch_bounds__(512) void k_gemm2(
    const unsigned short* __restrict__ y3T,
    const unsigned short* __restrict__ w2bf,
    const float* __restrict__ b2, const float* __restrict__ g2,
    const float* __restrict__ bb2,const float* __restrict__ m2,
    const float* __restrict__ v2, float* __restrict__ out)
{
    const int ct  = blockIdx.x;        // 0..3   co-tile
    const int pb  = blockIdx.y;        // 0..63  1024-row slab of rg
    const int tid = threadIdx.x;       // 0..511
    const int co0 = ct * 128;
    const int row0 = pb * 1024;        // global row rg = nn*8192 + p

    __shared__ unsigned short As[65536];    // 128 KB persistent [co][512c] swz
    __shared__ unsigned short Bs[2][8192];  // 2 x 16 KB chunk-major [q][prow]

    const int lane = tid & 63, wv = tid >> 6;
    const int wr = wv >> 2, wc = wv & 3;          // 2 x 4 wave grid
    const int ln15 = lane & 15, quad = lane >> 4;

    const unsigned short* Ag = w2bf + (size_t)co0 * 512;
    const unsigned short* Bg = y3T;

    // ---- persistent A stage (verified in R2): LDS slot (r,s,j) holds
    // global chunk (s, j ^ (r&7)) ----
#pragma unroll
    for (int j = 0; j < 16; j++) {
        int r = wv * 16 + j;
        int s = lane >> 3, q = (lane & 7) ^ (r & 7);
        load_lds16(Ag + (size_t)r * 512 + s * 64 + q * 8, &As[r * 512]);
    }

    // ---- BN2 constants for this thread's 16 co values (4 mi x 4 r) ----
    float4 sc4[4], ba4[4];
#pragma unroll
    for (int mi = 0; mi < 4; mi++) {
        int cb = co0 + wr * 64 + mi * 16 + quad * 4;
        float4 g = *(const float4*)&g2[cb];
        float4 vr = *(const float4*)&v2[cb];
        float4 bb = *(const float4*)&b2[cb];
        float4 mm = *(const float4*)&m2[cb];
        float4 be = *(const float4*)&bb2[cb];
        float4 sc, ba;
        sc.x = g.x * rsqrtf(vr.x + EPS); ba.x = (bb.x - mm.x) * sc.x + be.x;
        sc.y = g.y * rsqrtf(vr.y + EPS); ba.y = (bb.y - mm.y) * sc.y + be.y;
        sc.z = g.z * rsqrtf(vr.z + EPS); ba.z = (bb.z - mm.z) * sc.z + be.z;
        sc.w = g.w * rsqrtf(vr.w + EPS); ba.w = (bb.w - mm.w) * sc.w + be.w;
        sc4[mi] = sc; ba4[mi] = ba;
    }

    f32x4 acc[4][4];
#pragma unroll
    for (int i = 0; i < 4; i++)
#pragma unroll
        for (int j = 0; j < 4; j++) acc[i][j] = (f32x4){0.f, 0.f, 0.f, 0.f};

    // B stage for iter 'it' into buffer 'b'. 16 blocks of 1 KB; block
    // d = wv*2+i stages c-chunk q=d>>2 for 64 consecutive rows pr0=(d&3)*64.
    // LDS ushort idx d*512 + lane*8 == q*2048 + (pr0+lane)*8  (chunk-major).
    auto stageB = [&](int it, int b) {
        int sub = it >> 4, c0 = (it & 15) * 32;
        size_t rgb = (size_t)row0 + sub * 256;
#pragma unroll
        for (int i = 0; i < 2; i++) {
            int d = wv * 2 + i;
            int q = d >> 2, pr0 = (d & 3) * 64;
            load_lds16(Bg + (rgb + pr0 + lane) * 512 + c0 + q * 8,
                       &Bs[b][d * 512]);
        }
    };

    stageB(0, 0);
    __syncthreads();   // drains A stage + B chunk 0

    // 64 iters: 4 p-subtiles (256 rows) x 16 c-steps (BK=32)
    for (int it = 0; it < 64; ++it) {
        const int cur = it & 1;
        if (it + 1 < 64) stageB(it + 1, cur ^ 1);  // prefetch under compute

        {
            int s     = (it & 15) >> 1;        // 64c slice = c0>>6
            int cbase = (it & 1) * 4;          // (c0>>3)&7
            bf16x8 a[4], b[4];
#pragma unroll
            for (int mi = 0; mi < 4; mi++) {
                int row = wr * 64 + mi * 16 + ln15;
                int cw  = (cbase + quad) ^ (row & 7);
                a[mi] = *(const bf16x8*)&As[row * 512 + s * 64 + cw * 8];
            }
#pragma unroll
            for (int pi = 0; pi < 4; pi++) {
                int prow = wc * 64 + pi * 16 + ln15;
                b[pi] = *(const bf16x8*)&Bs[cur][quad * 2048 + prow * 8];
            }
#pragma unroll
            for (int mi = 0; mi < 4; mi++)
#pragma unroll
                for (int pi = 0; pi < 4; pi++)
                    acc[mi][pi] = __builtin_amdgcn_mfma_f32_16x16x32_bf16(
                        a[mi], b[pi], acc[mi][pi], 0, 0, 0);
        }

        if ((it & 15) == 15) {   // subtile complete: BN2+ReLU epilogue
            int sub = it >> 4;
#pragma unroll
            for (int mi = 0; mi < 4; mi++) {
#pragma unroll
                for (int pi = 0; pi < 4; pi++) {
                    int rg = row0 + sub * 256 + wc * 64 + pi * 16 + ln15;
                    int nn = rg >> 13, p = rg & 8191;
                    const float* scp = (const float*)&sc4[mi];
                    const float* bap = (const float*)&ba4[mi];
#pragma unroll
                    for (int r = 0; r < 4; r++) {
                        int co = co0 + wr * 64 + mi * 16 + quad * 4 + r;
                        float vv = fmaxf(acc[mi][pi][r] * scp[r] + bap[r], 0.f);
                        __builtin_nontemporal_store(
                            vv, &out[((size_t)nn * 512 + co) * 8192 + p]);
                    }
                    acc[mi][pi] = (f32x4){0.f, 0.f, 0.f, 0.f};
                }
            }
        }
        __syncthreads();   // drains stage(it+1); orders buf overwrite at it+2
    }
}

// ---------------------------------------------------------------------------
extern "C" void kernel_launch(void* const* d_in, const int* in_sizes, int n_in,
                              void* d_out, int out_size, void* d_ws, size_t ws_size,
                              hipStream_t stream) {
    const float* x   = (const float*)d_in[0];
    const float* w1  = (const float*)d_in[1];
    const float* b1  = (const float*)d_in[2];
    const float* g1  = (const float*)d_in[3];
    const float* bb1 = (const float*)d_in[4];
    const float* m1  = (const float*)d_in[5];
    const float* v1  = (const float*)d_in[6];
    const float* pw  = (const float*)d_in[7];
    const float* pb  = (const float*)d_in[8];
    const float* qw  = (const float*)d_in[9];
    const float* qb  = (const float*)d_in[10];
    const float* tw  = (const float*)d_in[11];
    const float* tbv = (const float*)d_in[12];
    const float* w2  = (const float*)d_in[13];
    const float* b2  = (const float*)d_in[14];
    const float* g2  = (const float*)d_in[15];
    const float* bb2 = (const float*)d_in[16];
    const float* m2  = (const float*)d_in[17];
    const float* v2  = (const float*)d_in[18];

    float* ws  = (float*)d_ws;
    float* rp  = ws;            // 2048 floats
    float* cp  = ws + 2048;     // 2048
    float* tps = ws + 4096;     // 128
    float* P   = ws + 8192;     // 8192
    float* Q   = ws + 16384;    // 8192
    float* TM  = ws + 24576;    // 256
    unsigned short* w2bf = (unsigned short*)(ws + 32768);   // 262144 ushorts
    unsigned short* y3T  = (unsigned short*)(ws + 163840);  // 33554432 ushorts

    // zero the atomic-reduction region (ws is poisoned 0xAA by harness)
    hipMemsetAsync(ws, 0, 4224 * sizeof(float), stream);

    k_conv1_pool<<<dim3(4, 8, 8), 512, 0, stream>>>(x, w1, b1, g1, bb1, m1, v1,
                                                    w2, w2bf, rp, cp, tps);
    k_pqtm<<<dim3(8), 256, 0, stream>>>(rp, cp, tps, pw, pb, qw, qb, tw, tbv,
                                        P, Q, TM);
    k_mix<<<dim3(32, 16, 8), 256, 0, stream>>>(x, P, Q, TM, y3T);
    k_gemm2<<<dim3(4, 64), 512, 0, stream>>>(y3T, w2bf, b2, g2, bb2, m2, v2,
                                             (float*)d_out);
}

// Round 4
// 347.784 us; speedup vs baseline: 1.0664x; 1.0664x over previous
//
#include <hip/hip_runtime.h>
#include <math.h>

#define EPS 1e-5f
// dims: n=8, C=512, t=8, h=32, w=32, K=8, S=4 (hb=wb=8), TS=2 (tb=4), TK=8

typedef __bf16 bf16x8 __attribute__((ext_vector_type(8)));
typedef float f32x4 __attribute__((ext_vector_type(4)));

__device__ static inline unsigned short f2bf(float f) {
    unsigned u = __float_as_uint(f);
    unsigned r = (u + 0x7fffu + ((u >> 16) & 1u)) >> 16;  // RNE
    return (unsigned short)r;
}

__device__ static inline void load_lds16(const void* g, void* l) {
    __builtin_amdgcn_global_load_lds(
        (const __attribute__((address_space(1))) unsigned int*)g,
        (__attribute__((address_space(3))) unsigned int*)l, 16, 0, 0);
}

// ---------------------------------------------------------------------------
// K1: conv1(512->8)+BN1+ReLU on the fly; pools rp/cp/tp. Folds w2 fp32->bf16.
// (unchanged)
// ---------------------------------------------------------------------------
__global__ __launch_bounds__(512) void k_conv1_pool(
    const float* __restrict__ x,  const float* __restrict__ w1,
    const float* __restrict__ b1, const float* __restrict__ g1,
    const float* __restrict__ bb1,const float* __restrict__ m1,
    const float* __restrict__ v1,
    const float* __restrict__ w2, unsigned short* __restrict__ w2bf,
    float* __restrict__ rp, float* __restrict__ cp, float* __restrict__ tps)
{
    const int a   = blockIdx.x;   // 0..3 (h-block)
    const int t   = blockIdx.y;   // 0..7
    const int nn  = blockIdx.z;   // 0..7
    const int tid = threadIdx.x;  // 0..511
    const int wv  = tid >> 6;     // wave = output k
    const int lane= tid & 63;

    __shared__ float xs[2][8192];  // 2 x 32 KB: [buf][c(32)][pos(256)]

    // folded w2 cast (1 MB read total across grid)
    {
        int gid = (((nn * 8 + t) * 4 + a) * 512) + tid;
        if (gid < 65536) {
            float4 v = *(const float4*)&w2[gid * 4];
            ushort4 o;
            o.x = f2bf(v.x); o.y = f2bf(v.y); o.z = f2bf(v.z); o.w = f2bf(v.w);
            *(ushort4*)&w2bf[gid * 4] = o;
        }
    }

    const int k = __builtin_amdgcn_readfirstlane(wv);
    const float* xg = x + (size_t)nn * 512 * 8192 + t * 1024 + a * 256 + lane * 4;

#pragma unroll
    for (int i = 0; i < 4; i++) {
        int r = i * 8 + wv;
        load_lds16(xg + (size_t)r * 8192, &xs[0][r * 256]);
    }
    __syncthreads();

    f32x4 acc = (f32x4){0.f, 0.f, 0.f, 0.f};
    const float* wk = w1 + k * 512;   // wave-uniform -> s_load

    for (int ch = 0; ch < 16; ch++) {
        const int cur = ch & 1;
        if (ch < 15) {
#pragma unroll
            for (int i = 0; i < 4; i++) {
                int r = i * 8 + wv;
                load_lds16(xg + (size_t)((ch + 1) * 32 + r) * 8192,
                           &xs[cur ^ 1][r * 256]);
            }
        }
#pragma unroll
        for (int c = 0; c < 32; c++) {
            f32x4 xv = *(const f32x4*)&xs[cur][c * 256 + lane * 4];
            float wt = wk[ch * 32 + c];
            acc[0] += wt * xv[0];
            acc[1] += wt * xv[1];
            acc[2] += wt * xv[2];
            acc[3] += wt * xv[3];
        }
        __syncthreads();
    }

    {
        const float sc = g1[k] * rsqrtf(v1[k] + EPS);
        const float ba = (b1[k] - m1[k]) * sc + bb1[k];
        float o0 = fmaxf(acc[0] * sc + ba, 0.f);
        float o1 = fmaxf(acc[1] * sc + ba, 0.f);
        float o2 = fmaxf(acc[2] * sc + ba, 0.f);
        float o3 = fmaxf(acc[3] * sc + ba, 0.f);

        float m4 = fmaxf(fmaxf(o0, o1), fmaxf(o2, o3));
        float s4 = o0 + o1 + o2 + o3;

        float mr = m4;
#pragma unroll
        for (int m = 32; m >= 1; m >>= 1) mr = fmaxf(mr, __shfl_xor(mr, m, 64));
        if (lane == 0) rp[((nn * 8 + k) * 8 + t) * 4 + a] = mr;

        float mc = m4;
        mc = fmaxf(mc, __shfl_xor(mc, 1, 64));
        mc = fmaxf(mc, __shfl_xor(mc, 8, 64));
        mc = fmaxf(mc, __shfl_xor(mc, 16, 64));
        mc = fmaxf(mc, __shfl_xor(mc, 32, 64));
        if ((lane & 0x39) == 0)
            atomicMax((int*)&cp[((nn * 8 + k) * 8 + t) * 4 + (lane >> 1)],
                      __float_as_int(mc));

        float ss = s4;
#pragma unroll
        for (int m = 32; m >= 1; m >>= 1) ss += __shfl_xor(ss, m, 64);
        if (lane == 0) atomicAdd(&tps[(nn * 8 + k) * 2 + (t >> 2)], ss);
    }
}

// ---------------------------------------------------------------------------
// K2: conv_p/conv_q/conv_t + softmaxes -> P, Q, TM. grid (n=8), 256 threads.
// (unchanged)
// ---------------------------------------------------------------------------
__global__ __launch_bounds__(256) void k_pqtm(
    const float* __restrict__ rp, const float* __restrict__ cp,
    const float* __restrict__ tps,
    const float* __restrict__ pw, const float* __restrict__ pb,
    const float* __restrict__ qw, const float* __restrict__ qb,
    const float* __restrict__ tw, const float* __restrict__ tbv,
    float* __restrict__ P, float* __restrict__ Q, float* __restrict__ TM)
{
    const int nn  = blockIdx.x;
    const int tid = threadIdx.x;
    __shared__ float rps[256], cps[256], tpss[16];
    rps[tid] = rp[nn * 256 + tid];
    cps[tid] = cp[nn * 256 + tid];
    if (tid < 16) tpss[tid] = tps[nn * 16 + tid] * (1.0f / 4096.0f);
    __syncthreads();

    {   // p: tid = k*32 + a*8 + t; softmax over b
        int k = tid >> 5, a = (tid >> 3) & 3, t = tid & 7;
        float v[4];
#pragma unroll
        for (int b = 0; b < 4; b++) {
            int o = k * 16 + a * 4 + b;
            float s = pb[o];
#pragma unroll
            for (int c = 0; c < 8; c++)
#pragma unroll
                for (int i = 0; i < 4; i++)
                    s += pw[o * 32 + c * 4 + i] * rps[c * 32 + t * 4 + i];
            v[b] = s;
        }
        float mx = fmaxf(fmaxf(v[0], v[1]), fmaxf(v[2], v[3]));
        float e[4]; float sum = 0.f;
#pragma unroll
        for (int b = 0; b < 4; b++) { e[b] = expf(v[b] - mx); sum += e[b]; }
        float inv = 1.f / sum;
        int base = ((nn * 8 + k) * 8 + t) * 16 + a * 4;
#pragma unroll
        for (int b = 0; b < 4; b++) P[base + b] = e[b] * inv;
    }
    {   // q: tid = k*32 + b*8 + t; softmax over a
        int k = tid >> 5, b = (tid >> 3) & 3, t = tid & 7;
        float v[4];
#pragma unroll
        for (int a = 0; a < 4; a++) {
            int o = k * 16 + a * 4 + b;
            float s = qb[o];
#pragma unroll
            for (int c = 0; c < 8; c++)
#pragma unroll
                for (int i = 0; i < 4; i++)
                    s += qw[o * 32 + c * 4 + i] * cps[c * 32 + t * 4 + i];
            v[a] = s;
        }
        float mx = fmaxf(fmaxf(v[0], v[1]), fmaxf(v[2], v[3]));
        float e[4]; float sum = 0.f;
#pragma unroll
        for (int a = 0; a < 4; a++) { e[a] = expf(v[a] - mx); sum += e[a]; }
        float inv = 1.f / sum;
        int base = ((nn * 8 + k) * 8 + t) * 16 + b;
#pragma unroll
        for (int a = 0; a < 4; a++) Q[base + a * 4] = e[a] * inv;
    }
    if (tid < 16) {  // tm
        int kk = tid >> 1, a2 = tid & 1;
        float v[2];
#pragma unroll
        for (int b2 = 0; b2 < 2; b2++) {
            int o = kk * 4 + a2 * 2 + b2;
            float s = tbv[o];
#pragma unroll
            for (int c = 0; c < 8; c++)
#pragma unroll
                for (int i = 0; i < 2; i++)
                    s += tw[o * 16 + c * 2 + i] * tpss[c * 2 + i];
            v[b2] = s;
        }
        float mx = fmaxf(v[0], v[1]);
        float e0 = expf(v[0] - mx), e1 = expf(v[1] - mx);
        float inv = 1.f / (e0 + e1);
        TM[nn * 32 + kk * 4 + a2 * 2 + 0] = e0 * inv;
        TM[nn * 32 + kk * 4 + a2 * 2 + 1] = e1 * inv;
    }
}

// ---------------------------------------------------------------------------
// K3a: block-linear mixing -> y3T[n][p][c] (bf16, k-major). (unchanged)
// grid (u2*8+u = 32, cg32 = 16, n = 8) = 4096 blocks, 256 threads.
// ---------------------------------------------------------------------------
__global__ __launch_bounds__(256) void k_mix(
    const float* __restrict__ x, const float* __restrict__ P,
    const float* __restrict__ Q, const float* __restrict__ TM,
    unsigned short* __restrict__ y3T)
{
    const int u2  = blockIdx.x >> 3;   // 0..3 (t-pair)
    const int u   = blockIdx.x & 7;    // 0..7 (row-within-h-block)
    const int cg  = blockIdx.y;        // 0..15 (32-channel group)
    const int nn  = blockIdx.z;        // 0..7
    const int tid = threadIdx.x;       // 0..255
    const int kc  = cg >> 1;           // 64-chan group index for P/Q/TM

    __shared__ float xs[8192];             // 32 KB: 256 rows x 32 w, swizzled
    __shared__ unsigned short ys[8192];    // 16 KB: [tt][a][w][c32]

    const size_t xbase = (size_t)nn * 512 * 8192 + (size_t)cg * 32 * 8192;
#pragma unroll
    for (int rr = 0; rr < 8; rr++) {
        int id  = rr * 256 + tid;
        int row = id >> 3;                 // (tt*4+b)*32 + c
        int jw  = (id & 7) ^ (row & 7);    // swizzled w-chunk
        int tt = row >> 7, b = (row >> 5) & 3, c = row & 31;
        load_lds16(x + xbase + (size_t)c * 8192
                     + (u2 + 4 * tt) * 1024 + (b * 8 + u) * 32 + jw * 4,
                   &xs[(rr * 256 + (tid & 192)) * 4]);
    }

    const int a = tid >> 6, vh = (tid >> 5) & 1, c = tid & 31;
    float Pt[2][4], Qt[2][4][4];
#pragma unroll
    for (int tt = 0; tt < 2; tt++) {
        const float* Pb = &P[((nn * 8 + kc) * 8 + (u2 + 4 * tt)) * 16];
        const float* Qb = &Q[((nn * 8 + kc) * 8 + (u2 + 4 * tt)) * 16];
#pragma unroll
        for (int b = 0; b < 4; b++) Pt[tt][b] = Pb[a * 4 + b];
#pragma unroll
        for (int aw = 0; aw < 4; aw++)
#pragma unroll
            for (int bw = 0; bw < 4; bw++) Qt[tt][aw][bw] = Qb[aw * 4 + bw];
    }
    const float* TMb = &TM[nn * 32 + kc * 4];
    const float tm00 = TMb[0], tm01 = TMb[1], tm10 = TMb[2], tm11 = TMb[3];
    __syncthreads();

    float y1[2][4][4];
#pragma unroll
    for (int tt = 0; tt < 2; tt++)
#pragma unroll
        for (int aw = 0; aw < 4; aw++)
#pragma unroll
            for (int vi = 0; vi < 4; vi++) y1[tt][aw][vi] = 0.f;
#pragma unroll
    for (int tt = 0; tt < 2; tt++) {
#pragma unroll
        for (int b = 0; b < 4; b++) {
            float pv = Pt[tt][b];
            int row = (tt * 4 + b) * 32 + c;
#pragma unroll
            for (int aw = 0; aw < 4; aw++) {
                int slot = (aw * 2 + vh) ^ (c & 7);
                float4 xv = *(const float4*)&xs[(row * 8 + slot) * 4];
                y1[tt][aw][0] += pv * xv.x;
                y1[tt][aw][1] += pv * xv.y;
                y1[tt][aw][2] += pv * xv.z;
                y1[tt][aw][3] += pv * xv.w;
            }
        }
    }
#pragma unroll
    for (int bw = 0; bw < 4; bw++) {
#pragma unroll
        for (int vi = 0; vi < 4; vi++) {
            float s0 = 0.f, s1 = 0.f;
#pragma unroll
            for (int aw = 0; aw < 4; aw++) {
                s0 += Qt[0][aw][bw] * y1[0][aw][vi];
                s1 += Qt[1][aw][bw] * y1[1][aw][vi];
            }
            int wout = bw * 8 + vh * 4 + vi;
            ys[((0 + a) * 32 + wout) * 32 + c] = f2bf(tm00 * s0 + tm01 * s1);
            ys[((4 + a) * 32 + wout) * 32 + c] = f2bf(tm10 * s0 + tm11 * s1);
        }
    }
    __syncthreads();

#pragma unroll
    for (int it = 0; it < 4; it++) {
        int id  = it * 256 + tid;
        int row = id >> 2, jc = id & 3;    // row = (tt*4+a)*32 + w
        int tt = row >> 7, aa = (row >> 5) & 3, w = row & 31;
        int p = (u2 + 4 * tt) * 1024 + (aa * 8 + u) * 32 + w;
        uint4 val = *(const uint4*)&ys[row * 32 + jc * 8];
        *(uint4*)&y3T[((size_t)nn * 8192 + p) * 512 + cg * 32 + jc * 8] = val;
    }
}

// ---------------------------------------------------------------------------
// K3b: conv2 + BN2 + ReLU, bf16 MFMA GEMM — REVERTED to the R1-proven
// 128co x 128p / BK=64 / 4-wave structure (~4 blocks/CU, conflict-free frag
// reads). ONE delta vs R1: 1-D grid + bijective XCD chunk swizzle
// (wgid = (id&7)*256 + id>>3, 2048%8==0) so the 4 ct-blocks sharing a B-tile
// run consecutively on the SAME XCD -> B re-reads become L2 hits; w2bf
// becomes L2-resident per XCD.
// ---------------------------------------------------------------------------
__global__ __launch_bounds__(256) void k_gemm2(
    const unsigned short* __restrict__ y3T,
    const unsigned short* __restrict__ w2bf,
    const float* __restrict__ b2, const float* __restrict__ g2,
    const float* __restrict__ bb2,const float* __restrict__ m2,
    const float* __restrict__ v2, float* __restrict__ out)
{
    // XCD-aware bijective swizzle of the flat 2048-block grid
    const int id   = blockIdx.x;
    const int wgid = (id & 7) * 256 + (id >> 3);
    const int ct   = wgid & 3;          // co-tile (fastest within an XCD)
    const int pt   = (wgid >> 2) & 63;  // p-tile
    const int nn   = wgid >> 8;         // batch (one per XCD)

    const int tid = threadIdx.x;
    const int co0 = ct * 128, p0 = pt * 128;

    __shared__ unsigned short As[8192];  // 16 KB swizzled [co][c]
    __shared__ unsigned short Bs[8192];  // 16 KB swizzled [p][c]
    __shared__ float sc_s[128], ba_s[128];

    if (tid < 128) {
        int co = co0 + tid;
        float sc = g2[co] * rsqrtf(v2[co] + EPS);
        sc_s[tid] = sc;
        ba_s[tid] = (b2[co] - m2[co]) * sc + bb2[co];
    }

    const int lane = tid & 63, wv = tid >> 6;
    const int wr = wv >> 1, wc = wv & 1;
    const int ln15 = lane & 15, quad = lane >> 4;

    const int lrow = lane >> 3;
    const int jc   = (lane & 7) ^ lrow;

    f32x4 acc[4][4];
#pragma unroll
    for (int i = 0; i < 4; i++)
#pragma unroll
        for (int j = 0; j < 4; j++) acc[i][j] = (f32x4){0.f, 0.f, 0.f, 0.f};

    const unsigned short* Ag = w2bf + (size_t)co0 * 512;
    const unsigned short* Bg = y3T + ((size_t)nn * 8192 + p0) * 512;

    for (int c0 = 0; c0 < 512; c0 += 64) {
#pragma unroll
        for (int it = 0; it < 4; it++) {
            int rb = (wv * 4 + it) * 8;
            load_lds16(Ag + (size_t)(rb + lrow) * 512 + c0 + jc * 8,
                       &As[(wv * 4 + it) * 512]);
            load_lds16(Bg + (size_t)(rb + lrow) * 512 + c0 + jc * 8,
                       &Bs[(wv * 4 + it) * 512]);
        }
        __syncthreads();

#pragma unroll
        for (int ks = 0; ks < 2; ks++) {
            bf16x8 a[4], b[4];
#pragma unroll
            for (int mi = 0; mi < 4; mi++) {
                int row = wr * 64 + mi * 16 + ln15;
                int chunk = row * 8 + ((ks * 4 + quad) ^ (row & 7));
                a[mi] = *(const bf16x8*)&As[chunk * 8];
            }
#pragma unroll
            for (int pi = 0; pi < 4; pi++) {
                int row = wc * 64 + pi * 16 + ln15;
                int chunk = row * 8 + ((ks * 4 + quad) ^ (row & 7));
                b[pi] = *(const bf16x8*)&Bs[chunk * 8];
            }
#pragma unroll
            for (int mi = 0; mi < 4; mi++)
#pragma unroll
                for (int pi = 0; pi < 4; pi++)
                    acc[mi][pi] = __builtin_amdgcn_mfma_f32_16x16x32_bf16(
                        a[mi], b[pi], acc[mi][pi], 0, 0, 0);
        }
        __syncthreads();
    }

    // epilogue: BN2 + ReLU; nontemporal (write-once, keep LLC for y3T/x)
#pragma unroll
    for (int mi = 0; mi < 4; mi++) {
        int lco = wr * 64 + mi * 16 + quad * 4;
#pragma unroll
        for (int pi = 0; pi < 4; pi++) {
            int p = p0 + wc * 64 + pi * 16 + ln15;
#pragma unroll
            for (int r = 0; r < 4; r++) {
                float vv = fmaxf(acc[mi][pi][r] * sc_s[lco + r] + ba_s[lco + r],
                                 0.f);
                __builtin_nontemporal_store(
                    vv, &out[((size_t)nn * 512 + co0 + lco + r) * 8192 + p]);
            }
        }
    }
}

// ---------------------------------------------------------------------------
extern "C" void kernel_launch(void* const* d_in, const int* in_sizes, int n_in,
                              void* d_out, int out_size, void* d_ws, size_t ws_size,
                              hipStream_t stream) {
    const float* x   = (const float*)d_in[0];
    const float* w1  = (const float*)d_in[1];
    const float* b1  = (const float*)d_in[2];
    const float* g1  = (const float*)d_in[3];
    const float* bb1 = (const float*)d_in[4];
    const float* m1  = (const float*)d_in[5];
    const float* v1  = (const float*)d_in[6];
    const float* pw  = (const float*)d_in[7];
    const float* pb  = (const float*)d_in[8];
    const float* qw  = (const float*)d_in[9];
    const float* qb  = (const float*)d_in[10];
    const float* tw  = (const float*)d_in[11];
    const float* tbv = (const float*)d_in[12];
    const float* w2  = (const float*)d_in[13];
    const float* b2  = (const float*)d_in[14];
    const float* g2  = (const float*)d_in[15];
    const float* bb2 = (const float*)d_in[16];
    const float* m2  = (const float*)d_in[17];
    const float* v2  = (const float*)d_in[18];

    float* ws  = (float*)d_ws;
    float* rp  = ws;            // 2048 floats
    float* cp  = ws + 2048;     // 2048
    float* tps = ws + 4096;     // 128
    float* P   = ws + 8192;     // 8192
    float* Q   = ws + 16384;    // 8192
    float* TM  = ws + 24576;    // 256
    unsigned short* w2bf = (unsigned short*)(ws + 32768);   // 262144 ushorts
    unsigned short* y3T  = (unsigned short*)(ws + 163840);  // 33554432 ushorts

    // zero the atomic-reduction region (ws is poisoned 0xAA by harness)
    hipMemsetAsync(ws, 0, 4224 * sizeof(float), stream);

    k_conv1_pool<<<dim3(4, 8, 8), 512, 0, stream>>>(x, w1, b1, g1, bb1, m1, v1,
                                                    w2, w2bf, rp, cp, tps);
    k_pqtm<<<dim3(8), 256, 0, stream>>>(rp, cp, tps, pw, pb, qw, qb, tw, tbv,
                                        P, Q, TM);
    k_mix<<<dim3(32, 16, 8), 256, 0, stream>>>(x, P, Q, TM, y3T);
    k_gemm2<<<dim3(2048), 256, 0, stream>>>(y3T, w2bf, b2, g2, bb2, m2, v2,
                                            (float*)d_out);
}